// Round 1
// baseline (213.483 us; speedup 1.0000x reference)
//
#include <hip/hip_runtime.h>
#include <cstdint>
#include <cstddef>

// Problem constants (from reference)
#define N_EMBD 1024
#define T_SEQ  2048
#define NBATCH 4
#define SPAN   256
#define C3     3072
// scale = sqrt(N_EMBD * SPAN) = sqrt(262144) = 512

typedef float  floatx4 __attribute__((ext_vector_type(4)));
typedef __bf16 bf16x8  __attribute__((ext_vector_type(8)));

// float -> bf16 (round-to-nearest-even), as raw ushort
__device__ inline unsigned short f2bf(float f) {
    union { float f; unsigned u; } x; x.f = f;
    unsigned u = x.u;
    unsigned r = (u + 0x7fffu + ((u >> 16) & 1u)) >> 16;
    return (unsigned short)r;
}

// async global->LDS, 16B per lane. LDS dest = wave-uniform base + lane*16.
typedef __attribute__((address_space(1))) const void GVOID;
typedef __attribute__((address_space(3))) void LVOID;
__device__ inline void gl2lds16(const void* g, void* l) {
    __builtin_amdgcn_global_load_lds((GVOID*)g, (LVOID*)l, 16, 0, 0);
}

// ---------------------------------------------------------------------------
// K0a: convert x fp32 -> bf16 (8192x1024)
__global__ __launch_bounds__(256) void k_cvt_x(const float* __restrict__ x,
                                               unsigned short* __restrict__ xb) {
    int i = (blockIdx.x * 256 + threadIdx.x) * 4;
    float4 v = *(const float4*)(x + i);
    ushort4 o;
    o.x = f2bf(v.x); o.y = f2bf(v.y); o.z = f2bf(v.z); o.w = f2bf(v.w);
    *(ushort4*)(xb + i) = o;
}

// ---------------------------------------------------------------------------
// K0b: W [1024 x 3072] fp32 -> WbT [3072 x 1024] bf16 (LDS tile transpose)
__global__ __launch_bounds__(256) void k_cvt_w_t(const float* __restrict__ W,
                                                 unsigned short* __restrict__ WbT) {
    __shared__ unsigned short t[32][33];
    int tx = threadIdx.x & 31, ty = threadIdx.x >> 5;
    int k0 = blockIdx.x * 32, n0 = blockIdx.y * 32;
#pragma unroll
    for (int i = 0; i < 4; i++) {
        int k = k0 + ty + i * 8;
        t[ty + i * 8][tx] = f2bf(W[(size_t)k * C3 + n0 + tx]);
    }
    __syncthreads();
#pragma unroll
    for (int i = 0; i < 4; i++) {
        int n = n0 + ty + i * 8;
        WbT[(size_t)n * N_EMBD + k0 + tx] = t[tx][ty + i * 8];
    }
}

// ---------------------------------------------------------------------------
// K1: qkv[8192 x 3072] bf16 = Xb[8192x1024] @ WbT^T + b   (128x128 tile, BK=32)
__global__ __launch_bounds__(256) void k_qkv_gemm(const unsigned short* __restrict__ Xb,
                                                  const unsigned short* __restrict__ WbT,
                                                  const float* __restrict__ bqkv,
                                                  unsigned short* __restrict__ qkv) {
    __shared__ unsigned short As[128 * 32];
    __shared__ unsigned short Bs[128 * 32];
    const int tid = threadIdx.x, lane = tid & 63, wave = tid >> 6;
    const int n0 = blockIdx.x * 128, m0 = blockIdx.y * 128;
    const int wr = wave >> 1, wc = wave & 1;

    floatx4 acc[4][4] = {};

    const int srow = wave * 16 + (lane >> 2);   // 0..63 across 4 waves
    const int scol = (lane & 3) * 8;            // element offset within 32-wide K tile
    const unsigned short* gA = Xb  + (size_t)(m0 + srow) * N_EMBD + scol;
    const unsigned short* gB = WbT + (size_t)(n0 + srow) * N_EMBD + scol;

    for (int k0 = 0; k0 < N_EMBD; k0 += 32) {
        gl2lds16(gA + k0,              &As[(wave * 16) * 32]);
        gl2lds16(gA + 64 * N_EMBD + k0, &As[(64 + wave * 16) * 32]);
        gl2lds16(gB + k0,              &Bs[(wave * 16) * 32]);
        gl2lds16(gB + 64 * N_EMBD + k0, &Bs[(64 + wave * 16) * 32]);
        __syncthreads();

        bf16x8 a[4], b[4];
        const int qk = (lane >> 4) * 8;
        const int ra = wr * 64 + (lane & 15);
        const int rb = wc * 64 + (lane & 15);
#pragma unroll
        for (int mi = 0; mi < 4; mi++) a[mi] = *(const bf16x8*)&As[(ra + mi * 16) * 32 + qk];
#pragma unroll
        for (int ni = 0; ni < 4; ni++) b[ni] = *(const bf16x8*)&Bs[(rb + ni * 16) * 32 + qk];
#pragma unroll
        for (int mi = 0; mi < 4; mi++)
#pragma unroll
            for (int ni = 0; ni < 4; ni++)
                acc[mi][ni] = __builtin_amdgcn_mfma_f32_16x16x32_bf16(a[mi], b[ni], acc[mi][ni], 0, 0, 0);
        __syncthreads();
    }

    // epilogue: + bias, cvt bf16, store
    const int cn = lane & 15, q = lane >> 4;
#pragma unroll
    for (int ni = 0; ni < 4; ni++) {
        const int n = n0 + wc * 64 + ni * 16 + cn;
        const float bias = bqkv[n];
#pragma unroll
        for (int mi = 0; mi < 4; mi++) {
            const int mbase = m0 + wr * 64 + mi * 16 + q * 4;
#pragma unroll
            for (int r = 0; r < 4; r++)
                qkv[(size_t)(mbase + r) * C3 + n] = f2bf(acc[mi][ni][r] + bias);
        }
    }
}

// ---------------------------------------------------------------------------
// K1.5: V slice of qkv -> Vt[b][c][t] bf16 (LDS tile transpose)
__global__ __launch_bounds__(256) void k_v_t(const unsigned short* __restrict__ qkv,
                                             unsigned short* __restrict__ Vt) {
    __shared__ unsigned short t[32][33];
    int tx = threadIdx.x & 31, ty = threadIdx.x >> 5;
    int t0 = blockIdx.x * 32, c0 = blockIdx.y * 32, b = blockIdx.z;
#pragma unroll
    for (int i = 0; i < 4; i++) {
        int tt = t0 + ty + i * 8;
        t[ty + i * 8][tx] = qkv[(size_t)(b * T_SEQ + tt) * C3 + 2048 + c0 + tx];
    }
    __syncthreads();
#pragma unroll
    for (int i = 0; i < 4; i++) {
        int c = c0 + ty + i * 8;
        Vt[(size_t)b * N_EMBD * T_SEQ + (size_t)c * T_SEQ + t0 + tx] = t[tx][ty + i * 8];
    }
}

// ---------------------------------------------------------------------------
// K2a: banded scores. grid (jj=5, qb=32, b=4). Each WG: S[64x64] = Q(64x1024) . K(64x1024)^T
__global__ __launch_bounds__(256) void k_scores(const unsigned short* __restrict__ qkv,
                                                unsigned short* __restrict__ S) {
    const int jj = blockIdx.x, qb = blockIdx.y, b = blockIdx.z;
    const int jb = qb - 4 + jj;
    if (jb < 0) return;

    __shared__ unsigned short Qs[64 * 64];
    __shared__ unsigned short Ks[64 * 64];
    const int tid = threadIdx.x, lane = tid & 63, wave = tid >> 6;
    const int wr = wave >> 1, wc = wave & 1;

    floatx4 acc[2][2] = {};

    const int srow = wave * 8 + (lane >> 3);    // 0..31 across 4 waves
    const int scol = (lane & 7) * 8;
    const unsigned short* gQ = qkv + (size_t)(b * T_SEQ + qb * 64 + srow) * C3 + scol;
    const unsigned short* gK = qkv + (size_t)(b * T_SEQ + jb * 64 + srow) * C3 + 1024 + scol;

    for (int k0 = 0; k0 < N_EMBD; k0 += 64) {
        gl2lds16(gQ + k0,                   &Qs[(wave * 8) * 64]);
        gl2lds16(gQ + (size_t)32 * C3 + k0, &Qs[(32 + wave * 8) * 64]);
        gl2lds16(gK + k0,                   &Ks[(wave * 8) * 64]);
        gl2lds16(gK + (size_t)32 * C3 + k0, &Ks[(32 + wave * 8) * 64]);
        __syncthreads();
#pragma unroll
        for (int ks = 0; ks < 2; ks++) {
            bf16x8 a[2], bb[2];
            const int qk = ks * 32 + (lane >> 4) * 8;
#pragma unroll
            for (int mi = 0; mi < 2; mi++) a[mi]  = *(const bf16x8*)&Qs[(wr * 32 + mi * 16 + (lane & 15)) * 64 + qk];
#pragma unroll
            for (int ni = 0; ni < 2; ni++) bb[ni] = *(const bf16x8*)&Ks[(wc * 32 + ni * 16 + (lane & 15)) * 64 + qk];
#pragma unroll
            for (int mi = 0; mi < 2; mi++)
#pragma unroll
                for (int ni = 0; ni < 2; ni++)
                    acc[mi][ni] = __builtin_amdgcn_mfma_f32_16x16x32_bf16(a[mi], bb[ni], acc[mi][ni], 0, 0, 0);
        }
        __syncthreads();
    }

    unsigned short* Sb = S + (((size_t)(b * 32 + qb) * 5 + jj) << 12);
    const int cn = lane & 15, q = lane >> 4;
#pragma unroll
    for (int mi = 0; mi < 2; mi++)
#pragma unroll
        for (int ni = 0; ni < 2; ni++)
#pragma unroll
            for (int r = 0; r < 4; r++) {
                const int il = wr * 32 + mi * 16 + q * 4 + r;
                const int jl = wc * 32 + ni * 16 + cn;
                const int gi = qb * 64 + il, gj = jb * 64 + jl;
                const float v = ((gj <= gi) && (gj > gi - 256)) ? acc[mi][ni][r] * (1.0f / 512.0f) : 0.0f;
                Sb[il * 64 + jl] = f2bf(v);
            }
}

// ---------------------------------------------------------------------------
// K2b: out[64 x 128] = sum_jj S[qb][jj] (64x64) @ V[jb] (64x128). grid (cg=8, qb=32, b=4)
__global__ __launch_bounds__(256) void k_sv(const unsigned short* __restrict__ S,
                                            const unsigned short* __restrict__ Vt,
                                            float* __restrict__ out) {
    const int cg = blockIdx.x, qb = blockIdx.y, b = blockIdx.z;
    const int c0 = cg * 128;

    __shared__ unsigned short Ss[64 * 64];
    __shared__ unsigned short Vs[128 * 64];
    const int tid = threadIdx.x, lane = tid & 63, wave = tid >> 6;
    const int wr = wave >> 1, wc = wave & 1;

    floatx4 acc[2][4] = {};

    const int srow = wave * 8 + (lane >> 3);
    const int scol = (lane & 7) * 8;

    for (int jj = 0; jj < 5; jj++) {
        const int jb = qb - 4 + jj;
        if (jb < 0) continue;

        const unsigned short* gS = S + (((size_t)(b * 32 + qb) * 5 + jj) << 12) + srow * 64 + scol;
        gl2lds16(gS,           &Ss[(wave * 8) * 64]);
        gl2lds16(gS + 32 * 64, &Ss[(32 + wave * 8) * 64]);
        const unsigned short* gV = Vt + (size_t)b * N_EMBD * T_SEQ
                                      + (size_t)(c0 + srow) * T_SEQ + jb * 64 + scol;
#pragma unroll
        for (int is = 0; is < 4; is++)
            gl2lds16(gV + (size_t)is * 32 * T_SEQ, &Vs[(is * 32 + wave * 8) * 64]);
        __syncthreads();
#pragma unroll
        for (int ks = 0; ks < 2; ks++) {
            bf16x8 a[2], bb[4];
            const int qk = ks * 32 + (lane >> 4) * 8;
#pragma unroll
            for (int mi = 0; mi < 2; mi++) a[mi]  = *(const bf16x8*)&Ss[(wr * 32 + mi * 16 + (lane & 15)) * 64 + qk];
#pragma unroll
            for (int ni = 0; ni < 4; ni++) bb[ni] = *(const bf16x8*)&Vs[(wc * 64 + ni * 16 + (lane & 15)) * 64 + qk];
#pragma unroll
            for (int mi = 0; mi < 2; mi++)
#pragma unroll
                for (int ni = 0; ni < 4; ni++)
                    acc[mi][ni] = __builtin_amdgcn_mfma_f32_16x16x32_bf16(a[mi], bb[ni], acc[mi][ni], 0, 0, 0);
        }
        __syncthreads();
    }

    const int cn = lane & 15, q = lane >> 4;
#pragma unroll
    for (int mi = 0; mi < 2; mi++)
#pragma unroll
        for (int ni = 0; ni < 4; ni++)
#pragma unroll
            for (int r = 0; r < 4; r++) {
                const int il = wr * 32 + mi * 16 + q * 4 + r;
                const int cl = wc * 64 + ni * 16 + cn;
                out[(size_t)(b * T_SEQ + qb * 64 + il) * N_EMBD + c0 + cl] = acc[mi][ni][r];
            }
}

// ---------------------------------------------------------------------------
// K3: in-place LayerNorm over last dim (1024), one WG per row
__global__ __launch_bounds__(256) void k_ln(float* __restrict__ out,
                                            const float* __restrict__ w,
                                            const float* __restrict__ bias) {
    __shared__ float red[8];
    const int t = threadIdx.x;
    float* p = out + (size_t)blockIdx.x * N_EMBD;
    float4 v = ((const float4*)p)[t];
    float s  = v.x + v.y + v.z + v.w;
    float sq = v.x * v.x + v.y * v.y + v.z * v.z + v.w * v.w;
#pragma unroll
    for (int off = 32; off; off >>= 1) {
        s  += __shfl_down(s, off, 64);
        sq += __shfl_down(sq, off, 64);
    }
    const int wave = t >> 6, lane = t & 63;
    if (lane == 0) { red[wave] = s; red[4 + wave] = sq; }
    __syncthreads();
    const float ts = red[0] + red[1] + red[2] + red[3];
    const float tq = red[4] + red[5] + red[6] + red[7];
    const float mean = ts * (1.0f / N_EMBD);
    const float var  = tq * (1.0f / N_EMBD) - mean * mean;
    const float rs = rsqrtf(var + 1e-5f);
    float4 wv = ((const float4*)w)[t];
    float4 bv = ((const float4*)bias)[t];
    float4 o;
    o.x = (v.x - mean) * rs * wv.x + bv.x;
    o.y = (v.y - mean) * rs * wv.y + bv.y;
    o.z = (v.z - mean) * rs * wv.z + bv.z;
    o.w = (v.w - mean) * rs * wv.w + bv.w;
    ((float4*)p)[t] = o;
}

// ---------------------------------------------------------------------------
extern "C" void kernel_launch(void* const* d_in, const int* in_sizes, int n_in,
                              void* d_out, int out_size, void* d_ws, size_t ws_size,
                              hipStream_t stream) {
    const float* x  = (const float*)d_in[0];
    const float* W  = (const float*)d_in[1];
    const float* bq = (const float*)d_in[2];
    const float* lw = (const float*)d_in[3];
    const float* lb = (const float*)d_in[4];
    float* out = (float*)d_out;
    char* ws = (char*)d_ws;

    // workspace layout (bytes). Sbuf aliases Xb (Xb dead after K1; K2a runs after K1).
    unsigned short* Xb   = (unsigned short*)(ws + 0);           // 16 MB  (8192x1024 bf16)
    unsigned short* Sbuf = (unsigned short*)(ws + 0);           // 5.25 MB, reuses Xb region
    unsigned short* WbT  = (unsigned short*)(ws + 16777216);    // 6 MB   (3072x1024 bf16)
    unsigned short* qkv  = (unsigned short*)(ws + 23068672);    // 48 MB  (8192x3072 bf16)
    unsigned short* Vt   = (unsigned short*)(ws + 73400320);    // 16 MB  (4x1024x2048 bf16)
    // total: 90,177,536 bytes

    k_cvt_x   <<<8192,            256, 0, stream>>>(x, Xb);
    k_cvt_w_t <<<dim3(32, 96),    256, 0, stream>>>(W, WbT);
    k_qkv_gemm<<<dim3(24, 64),    256, 0, stream>>>(Xb, WbT, bq, qkv);
    k_v_t     <<<dim3(64, 32, 4), 256, 0, stream>>>(qkv, Vt);
    k_scores  <<<dim3(5, 32, 4),  256, 0, stream>>>(qkv, Sbuf);
    k_sv      <<<dim3(8, 32, 4),  256, 0, stream>>>(Sbuf, Vt, out);
    k_ln      <<<8192,            256, 0, stream>>>(out, lw, lb);
}